// Round 15
// baseline (162.758 us; speedup 1.0000x reference)
//
#include <hip/hip_runtime.h>

#define S_LEN 4096
#define DIM   1024
#define NH    16
#define HD    64

typedef __bf16 bf16;
typedef __attribute__((ext_vector_type(8)))  __bf16 bf16x8;
typedef __attribute__((ext_vector_type(4)))  float  f32x4;
typedef __attribute__((ext_vector_type(16))) float  f32x16;
typedef __attribute__((ext_vector_type(4)))  unsigned int uint4v;

typedef __attribute__((address_space(3))) void lds_void;
typedef __attribute__((address_space(1))) void g_void;

#if __has_builtin(__builtin_amdgcn_exp2f)
#define EXP2(x) __builtin_amdgcn_exp2f(x)
#else
#define EXP2(x) exp2f(x)
#endif

// async global->LDS, 16B per lane. LDS dest = wave-uniform base + lane*16.
__device__ __forceinline__ void gl_lds16(const void* g, void* l) {
    __builtin_amdgcn_global_load_lds((g_void*)(void*)g, (lds_void*)l, 16, 0, 0);
}

// pack 2 floats -> 2 bf16 in a dword (v_cvt_pk_bf16_f32)
__device__ __forceinline__ unsigned int pk2(float a, float b) {
    unsigned short ua = __builtin_bit_cast(unsigned short, (bf16)a);
    unsigned short ub = __builtin_bit_cast(unsigned short, (bf16)b);
    return (unsigned int)ua | ((unsigned int)ub << 16);
}

// key-axis permutation for V^T: swap bits 2<->3 (involution, closed within
// each 16-slot MFMA group). Makes PV's A-fragment lane-local (no shuffles).
__device__ __forceinline__ int ksw23(int x) {
    return (x & ~12) | ((x & 8) >> 1) | ((x & 4) << 1);
}

// ---------------- fused fp32 -> bf16 conversions (1 launch, G13) ----------
__global__ __launch_bounds__(256) void f2b_all(
    const float* __restrict__ x,  const float* __restrict__ wq,
    const float* __restrict__ wk, const float* __restrict__ wv,
    const float* __restrict__ wo,
    bf16* __restrict__ xb, bf16* __restrict__ wqkv, bf16* __restrict__ wob)
{
    int b = blockIdx.x;
    const float* src; bf16* dst; int base;
    if (b < 2048)      { src = x;  dst = xb;              base = b; }
    else if (b < 2560) { src = wq; dst = wqkv;            base = b - 2048; }
    else if (b < 3072) { src = wk; dst = wqkv + 1048576;  base = b - 2560; }
    else if (b < 3584) { src = wv; dst = wqkv + 2097152;  base = b - 3072; }
    else               { src = wo; dst = wob;             base = b - 3584; }
    int i = base * 2048 + threadIdx.x * 8;
    float4 a = *(const float4*)(src + i);
    float4 c = *(const float4*)(src + i + 4);
    bf16x8 r;
    r[0]=(bf16)a.x; r[1]=(bf16)a.y; r[2]=(bf16)a.z; r[3]=(bf16)a.w;
    r[4]=(bf16)c.x; r[5]=(bf16)c.y; r[6]=(bf16)c.z; r[7]=(bf16)c.w;
    *(bf16x8*)(dst + i) = r;
}

// ---------------- m97-style QKV GEMM with fused epilogues (r12-proven) ----
// C = A * B^T (A[M][K], B[N][K]).
//   bn<8  -> Q: fused RMSNorm+RoPE from fp32 acc, outQ[h][s][d] bf16
//   bn<16 -> K: same, pre-swizzled (d ^ ((s&7)<<3))
//   bn>=16-> V^T: outV = vt[H][64][S_LEN], ksw23 key perm + (d&7)<<3 swizzle
// Fusion layout fact: the 16 lanes sharing g hold all 64 dims of one
// head-row (cols n*16+r): sum(x^2) = 4 in-lane squares + shfl_xor 1/2/4/8;
// RoPE partner (d +/- 32) is IN-LANE (n <-> n^2).
__global__ __launch_bounds__(256) void gemm_qkv(
    const bf16* __restrict__ A, const bf16* __restrict__ B,
    bf16* __restrict__ outQ, bf16* __restrict__ outK, bf16* __restrict__ outV,
    const float* __restrict__ cosb, const float* __restrict__ sinb,
    const float* __restrict__ qw,   const float* __restrict__ kw)
{
    const int K = 1024;
    __shared__ bf16 As[128][32];
    __shared__ bf16 Bs[128][32];
    const int bm = blockIdx.x, bn = blockIdx.y;
    const int tid  = threadIdx.x;
    const int wave = tid >> 6, lane = tid & 63;
    const int g = lane >> 4, r = lane & 15;
    const int wr = wave >> 1, wc = wave & 1;
    const int rr = lane >> 2, cc = (lane & 3) * 8;

    f32x4 acc[4][4] = {};

    const bf16* Ab = A + (size_t)(bm * 128) * K;
    const bf16* Bb = B + (size_t)(bn * 128) * K;

    for (int k0 = 0; k0 < K; k0 += 32) {
        #pragma unroll
        for (int i = 0; i < 2; ++i) {
            gl_lds16(Ab + (size_t)(wave*32 + i*16 + rr) * K + k0 + cc, &As[wave*32 + i*16][0]);
            gl_lds16(Bb + (size_t)(wave*32 + i*16 + rr) * K + k0 + cc, &Bs[wave*32 + i*16][0]);
        }
        __syncthreads();
        bf16x8 a[4], b[4];
        #pragma unroll
        for (int m = 0; m < 4; ++m) a[m] = *(const bf16x8*)&As[wr*64 + m*16 + r][g*8];
        #pragma unroll
        for (int n = 0; n < 4; ++n) b[n] = *(const bf16x8*)&Bs[wc*64 + n*16 + r][g*8];
        #pragma unroll
        for (int m = 0; m < 4; ++m)
            #pragma unroll
            for (int n = 0; n < 4; ++n)
                acc[m][n] = __builtin_amdgcn_mfma_f32_16x16x32_bf16(a[m], b[n], acc[m][n], 0, 0, 0);
        __syncthreads();
    }

    if (bn >= 16) {
        // V^T scatter with key permutation + pre-swizzle
        #pragma unroll
        for (int m = 0; m < 4; ++m)
            #pragma unroll
            for (int n = 0; n < 4; ++n)
                #pragma unroll
                for (int i = 0; i < 4; ++i) {
                    int row = bm*128 + wr*64 + m*16 + g*4 + i;
                    int col = bn*128 + wc*64 + n*16 + r;
                    int c2 = col - 2048;
                    int hh = c2 >> 6, d = c2 & 63;
                    int pos = ksw23(row & 63) ^ ((d & 7) << 3);
                    outV[((size_t)(hh * HD + d)) * S_LEN + (row & ~63) + pos] = (bf16)acc[m][n][i];
                }
    } else {
        // fused RMSNorm + RoPE for Q (bn<8) / K (8<=bn<16)
        const bool isK = (bn >= 8);
        const float* wn = isK ? kw : qw;
        bf16* dst = isK ? outK : outQ;
        const int h = ((bn & 7) << 1) | wc;
        float wv4[4];
        #pragma unroll
        for (int n = 0; n < 4; ++n) wv4[n] = wn[n * 16 + r];
        #pragma unroll
        for (int m = 0; m < 4; ++m)
            #pragma unroll
            for (int i = 0; i < 4; ++i) {
                int srow = bm*128 + wr*64 + m*16 + g*4 + i;
                float ss = acc[m][0][i]*acc[m][0][i] + acc[m][1][i]*acc[m][1][i]
                         + acc[m][2][i]*acc[m][2][i] + acc[m][3][i]*acc[m][3][i];
                ss += __shfl_xor(ss, 1);
                ss += __shfl_xor(ss, 2);
                ss += __shfl_xor(ss, 4);
                ss += __shfl_xor(ss, 8);
                float rn = rsqrtf(ss * (1.0f / 64.0f) + 1e-6f);
                float xn0 = acc[m][0][i] * rn * wv4[0];
                float xn1 = acc[m][1][i] * rn * wv4[1];
                float xn2 = acc[m][2][i] * rn * wv4[2];
                float xn3 = acc[m][3][i] * rn * wv4[3];
                float c0 = cosb[srow * 32 + r],      c1 = cosb[srow * 32 + 16 + r];
                float s0 = sinb[srow * 32 + r],      s1 = sinb[srow * 32 + 16 + r];
                float y0 = xn0 * c0 - xn2 * s0;
                float y1 = xn1 * c1 - xn3 * s1;
                float y2 = xn2 * c0 + xn0 * s0;
                float y3 = xn3 * c1 + xn1 * s1;
                size_t ob = ((size_t)h * S_LEN + srow) * HD;
                if (isK) {
                    int sw = (srow & 7) << 3;
                    dst[ob + ((     r) ^ sw)] = (bf16)y0;
                    dst[ob + ((16 + r) ^ sw)] = (bf16)y1;
                    dst[ob + ((32 + r) ^ sw)] = (bf16)y2;
                    dst[ob + ((48 + r) ^ sw)] = (bf16)y3;
                } else {
                    dst[ob +      r] = (bf16)y0;
                    dst[ob + 16 + r] = (bf16)y1;
                    dst[ob + 32 + r] = (bf16)y2;
                    dst[ob + 48 + r] = (bf16)y3;
                }
            }
    }
}

// ---------------- out-projection GEMM with FUSED combine (128x128) -------
// A operand = (sum of 4 bf16 O-slabs) * rcp(sum of 4 l partials), computed
// during A-staging (reg path + ds_write); B stays on global_load_lds.
// __syncthreads drains both lgkmcnt (ds_write) and vmcnt (gl_lds), so the
// barrier structure is identical to the proven r12 gemm. Numerics match the
// old combine_kernel exactly (fp32 sum of bf16 partials x rcp).
// h = k0>>6 is K-step-uniform; inv_l recomputed only when h changes.
__global__ __launch_bounds__(256) void gemm_out_fused(
    const bf16* __restrict__ Opc, const float* __restrict__ lpc,
    const bf16* __restrict__ B, float* __restrict__ outF)
{
    const int K = 1024, N = 1024;
    __shared__ bf16 As[128][32];
    __shared__ bf16 Bs[128][32];
    const int bm = blockIdx.x, bn = blockIdx.y;
    const int tid  = threadIdx.x;
    const int wave = tid >> 6, lane = tid & 63;
    const int g = lane >> 4, r = lane & 15;
    const int wr = wave >> 1, wc = wave & 1;
    const int rr = lane >> 2, cc = (lane & 3) * 8;

    f32x4 acc[4][4] = {};

    const int s0 = bm * 128 + wave * 32 + rr;        // staged row, i=0
    const int s1 = s0 + 16;                          // staged row, i=1
    const bf16* Bb = B + (size_t)(bn * 128) * K;

    float inv0 = 0.f, inv1 = 0.f;

    for (int k0 = 0; k0 < K; k0 += 32) {
        if ((k0 & 63) == 0) {                        // h changed: refresh inv_l
            int h = k0 >> 6;
            float l0 = 0.f, l1 = 0.f;
            #pragma unroll
            for (int c = 0; c < 4; ++c) {
                l0 += lpc[c * (NH * S_LEN) + h * S_LEN + s0];
                l1 += lpc[c * (NH * S_LEN) + h * S_LEN + s1];
            }
            inv0 = __builtin_amdgcn_rcpf(l0);
            inv1 = __builtin_amdgcn_rcpf(l1);
        }
        // A staging: combine 4 slabs, normalize, pack, ds_write
        #pragma unroll
        for (int i = 0; i < 2; ++i) {
            const int s = i ? s1 : s0;
            const float inv = i ? inv1 : inv0;
            float sum[8] = {};
            #pragma unroll
            for (int c = 0; c < 4; ++c) {
                bf16x8 v = *(const bf16x8*)(Opc + (size_t)c * S_LEN * DIM
                                            + (size_t)s * DIM + k0 + cc);
                #pragma unroll
                for (int j = 0; j < 8; ++j) sum[j] += (float)v[j];
            }
            bf16x8 y;
            #pragma unroll
            for (int j = 0; j < 8; ++j) y[j] = (bf16)(sum[j] * inv);
            *(bf16x8*)&As[wave * 32 + i * 16 + rr][cc] = y;
        }
        // B staging (async)
        #pragma unroll
        for (int i = 0; i < 2; ++i)
            gl_lds16(Bb + (size_t)(wave*32 + i*16 + rr) * K + k0 + cc, &Bs[wave*32 + i*16][0]);
        __syncthreads();
        bf16x8 a[4], b[4];
        #pragma unroll
        for (int m = 0; m < 4; ++m) a[m] = *(const bf16x8*)&As[wr*64 + m*16 + r][g*8];
        #pragma unroll
        for (int n = 0; n < 4; ++n) b[n] = *(const bf16x8*)&Bs[wc*64 + n*16 + r][g*8];
        #pragma unroll
        for (int m = 0; m < 4; ++m)
            #pragma unroll
            for (int n = 0; n < 4; ++n)
                acc[m][n] = __builtin_amdgcn_mfma_f32_16x16x32_bf16(a[m], b[n], acc[m][n], 0, 0, 0);
        __syncthreads();
    }

    #pragma unroll
    for (int m = 0; m < 4; ++m)
        #pragma unroll
        for (int n = 0; n < 4; ++n)
            #pragma unroll
            for (int i = 0; i < 4; ++i) {
                int row = bm*128 + wr*64 + m*16 + g*4 + i;
                int col = bn*128 + wc*64 + n*16 + r;
                outF[(size_t)row * N + col] = acc[m][n][i];
            }
}

// ---------------- causal flash attention, 32x32 MFMA, 4-chunk split -------
// (unchanged from round 12 -- proven 62.3us, 64 VGPR, no spill)
__global__ __launch_bounds__(256, 4) void attn_kernel(
    const bf16* __restrict__ q, const bf16* __restrict__ k,
    const bf16* __restrict__ vt,
    bf16* __restrict__ Opc, float* __restrict__ lpc)
{
    __shared__ bf16 Ks[2][64][64];   // [keys][d], rows pre-swizzled
    __shared__ bf16 Vt[2][64][64];   // [d][keys], permuted+pre-swizzled

    const int idx = blockIdx.x;
    const int h = idx & 15;
    const int u = idx >> 4;
    const int qt = 31 - (u >> 2);
    const int c  = u & 3;
    const int nt = 2 * qt + 2;
    const int t0 = (c * nt) >> 2;
    const int t1 = ((c + 1) * nt) >> 2;

    const int q0 = qt * 128;
    const int tid = threadIdx.x;
    const int wave = tid >> 6, lane = tid & 63;
    const int l31 = lane & 31, hi = lane >> 5;

    const bf16* qh  = q  + (size_t)h * S_LEN * HD;
    const bf16* kh  = k  + (size_t)h * S_LEN * HD;
    const bf16* vth = vt + (size_t)h * HD * S_LEN;

    const int qrow = q0 + wave * 32 + l31;
    bf16x8 qf[4];
    #pragma unroll
    for (int ds4 = 0; ds4 < 4; ++ds4)
        qf[ds4] = *(const bf16x8*)(qh + (size_t)qrow * HD + ds4 * 16 + hi * 8);

    float l_run = 0.f;
    f32x16 acc_o[2] = {};

    const int srow = lane >> 3, scol = (lane & 7) * 8;
    const float C1 = 0.125f * 1.44269504088896f;   // scale * log2(e)
    const float C2 = 8.0f * 1.44269504088896f;     // static max * log2(e)

    auto stage = [&](int t, int buf) {
        const int k0 = t * 64;
        const bf16* kb = kh + (size_t)(k0 + wave * 16) * HD;
        gl_lds16(kb + (size_t)(srow    ) * HD + scol, &Ks[buf][wave * 16][0]);
        gl_lds16(kb + (size_t)(srow + 8) * HD + scol, &Ks[buf][wave * 16 + 8][0]);
        const bf16* vb = vth + (size_t)(wave * 16) * S_LEN + k0;
        gl_lds16(vb + (size_t)(srow    ) * S_LEN + scol, &Vt[buf][wave * 16][0]);
        gl_lds16(vb + (size_t)(srow + 8) * S_LEN + scol, &Vt[buf][wave * 16 + 8][0]);
    };

#define COMPUTE_TILE(T, BUF)                                                  \
    do {                                                                      \
        const int k0_ = (T) * 64;                                             \
        const bool masked_ = ((T) >= 2 * qt);                                 \
        f32x16 sacc_[2];                                                      \
        __builtin_amdgcn_s_setprio(1);                                        \
        _Pragma("unroll")                                                     \
        for (int kn = 0; kn < 2; ++kn) {                                      \
            const int krow = kn * 32 + l31;                                   \
            const int sw = (krow & 7) << 3;                                   \
            f32x16 z = {};                                                    \
            _Pragma("unroll")                                                 \
            for (int ds4 = 0; ds4 < 4; ++ds4) {                               \
                bf16x8 kfr = *(const bf16x8*)&Ks[BUF][krow][(ds4 * 16 + hi * 8) ^ sw]; \
                z = __builtin_amdgcn_mfma_f32_32x32x16_bf16(kfr, qf[ds4], z, 0, 0, 0); \
            }                                                                 \
            sacc_[kn] = z;                                                    \
        }                                                                     \
        __builtin_amdgcn_s_setprio(0);                                        \
        float p_[32];                                                         \
        _Pragma("unroll")                                                     \
        for (int kn = 0; kn < 2; ++kn)                                        \
            _Pragma("unroll")                                                 \
            for (int rg = 0; rg < 16; ++rg) {                                 \
                float e = EXP2(fmaf(sacc_[kn][rg], C1, -C2));                 \
                if (masked_) {                                                \
                    int kloc = kn * 32 + (rg & 3) + 8 * (rg >> 2) + 4 * hi;   \
                    if (k0_ + kloc > qrow) e = 0.f;                           \
                }                                                             \
                p_[kn * 16 + rg] = e;                                         \
            }                                                                 \
        float s0_ = 0.f, s1_ = 0.f, s2_ = 0.f, s3_ = 0.f;                     \
        _Pragma("unroll")                                                     \
        for (int j = 0; j < 8; ++j) {                                         \
            s0_ += p_[4*j];   s1_ += p_[4*j+1];                               \
            s2_ += p_[4*j+2]; s3_ += p_[4*j+3];                               \
        }                                                                     \
        float rs_ = (s0_ + s1_) + (s2_ + s3_);                                \
        rs_ += __shfl_xor(rs_, 32);                                           \
        l_run += rs_;                                                         \
        bf16x8 pa_[4];                                                        \
        _Pragma("unroll")                                                     \
        for (int ks4 = 0; ks4 < 4; ++ks4) {                                   \
            uint4v w_;                                                        \
            w_.x = pk2(p_[8*ks4+0], p_[8*ks4+1]);                             \
            w_.y = pk2(p_[8*ks4+2], p_[8*ks4+3]);                             \
            w_.z = pk2(p_[8*ks4+4], p_[8*ks4+5]);                             \
            w_.w = pk2(p_[8*ks4+6], p_[8*ks4+7]);                             \
            pa_[ks4] = __builtin_bit_cast(bf16x8, w_);                        \
        }                                                                     \
        __builtin_amdgcn_s_setprio(1);                                        \
        _Pragma("unroll")                                                     \
        for (int n = 0; n < 2; ++n) {                                         \
            const int d = n * 32 + l31;                                       \
            const int sw = (d & 7) << 3;                                      \
            f32x16 a = acc_o[n];                                              \
            _Pragma("unroll")                                                 \
            for (int ks4 = 0; ks4 < 4; ++ks4) {                               \
                bf16x8 vfr = *(const bf16x8*)&Vt[BUF][d][(ks4 * 16 + hi * 8) ^ sw]; \
                a = __builtin_amdgcn_mfma_f32_32x32x16_bf16(pa_[ks4], vfr, a, 0, 0, 0); \
            }                                                                 \
            acc_o[n] = a;                                                     \
        }                                                                     \
        __builtin_amdgcn_s_setprio(0);                                        \
    } while (0)

    if (t0 < t1) {
        stage(t0, 0);
        asm volatile("s_waitcnt vmcnt(0)" ::: "memory");
        __syncthreads();
        int t = t0;
        while (t + 2 <= t1) {
            stage(t + 1, 1);
            COMPUTE_TILE(t, 0);
            asm volatile("s_waitcnt vmcnt(0)" ::: "memory");
            __syncthreads();
            if (t + 2 < t1) stage(t + 2, 0);
            COMPUTE_TILE(t + 1, 1);
            asm volatile("s_waitcnt vmcnt(0)" ::: "memory");
            __syncthreads();
            t += 2;
        }
        if (t < t1) COMPUTE_TILE(t, 0);   // odd tail (already staged in buf0)
    }
#undef COMPUTE_TILE

    bf16* Op = Opc + (size_t)c * S_LEN * DIM;
    #pragma unroll
    for (int n = 0; n < 2; ++n)
        #pragma unroll
        for (int rg = 0; rg < 16; ++rg) {
            int s_abs = q0 + wave * 32 + (rg & 3) + 8 * (rg >> 2) + 4 * hi;
            Op[(size_t)s_abs * DIM + h * HD + n * 32 + l31] = (bf16)acc_o[n][rg];
        }
    if (lane < 32)
        lpc[c * (NH * S_LEN) + h * S_LEN + (q0 + wave * 32 + lane)] = l_run;
}

// ---------------------------------------------------------------------------
extern "C" void kernel_launch(void* const* d_in, const int* in_sizes, int n_in,
                              void* d_out, int out_size, void* d_ws, size_t ws_size,
                              hipStream_t stream)
{
    const float* x    = (const float*)d_in[0];
    const float* cosb = (const float*)d_in[1];
    const float* sinb = (const float*)d_in[2];
    const float* wq   = (const float*)d_in[4];
    const float* wk   = (const float*)d_in[5];
    const float* wv   = (const float*)d_in[6];
    const float* wo   = (const float*)d_in[7];
    const float* qw   = (const float*)d_in[8];
    const float* kw   = (const float*)d_in[9];

    char* ws = (char*)d_ws;
    const size_t MB = 1024 * 1024;
    // region map (MB), temporal reuse (59MB total):
    // [0,2)   wob (whole run)
    // [2,10)  q_ws  (gemm_qkv fused epilogue -> attn)
    // [10,18) k_ws  (pre-swizzled)
    // [18,26) vt_ws (pre-permuted V^T)
    // [26,58) Opc[4] bf16 slabs (attn -> gemm_out_fused); before attn this
    //         region hosts xb [26,34) + wqkv [34,40) (dead after QKV GEMM)
    // [58,59) lpc[4] fp32
    bf16*  wob   = (bf16*)(ws + 0);
    bf16*  q_ws  = (bf16*)(ws + 2 * MB);
    bf16*  k_ws  = (bf16*)(ws + 10 * MB);
    bf16*  vt_ws = (bf16*)(ws + 18 * MB);
    bf16*  Opc   = (bf16*)(ws + 26 * MB);
    bf16*  xb    = (bf16*)(ws + 26 * MB);
    bf16*  wqkv  = (bf16*)(ws + 34 * MB);
    float* lpc   = (float*)(ws + 58 * MB);

    f2b_all<<<4096, 256, 0, stream>>>(x, wq, wk, wv, wo, xb, wqkv, wob);

    gemm_qkv<<<dim3(32, 24), 256, 0, stream>>>(xb, wqkv, q_ws, k_ws, vt_ws,
                                               cosb, sinb, qw, kw);
    attn_kernel<<<2048, 256, 0, stream>>>(q_ws, k_ws, vt_ws, Opc, lpc);
    gemm_out_fused<<<dim3(32, 8), 256, 0, stream>>>(Opc, lpc, wob, (float*)d_out);
}

// Round 16
// 141.119 us; speedup vs baseline: 1.1533x; 1.1533x over previous
//
#include <hip/hip_runtime.h>

#define S_LEN 4096
#define DIM   1024
#define NH    16
#define HD    64

typedef __bf16 bf16;
typedef __attribute__((ext_vector_type(8)))  __bf16 bf16x8;
typedef __attribute__((ext_vector_type(4)))  float  f32x4;
typedef __attribute__((ext_vector_type(16))) float  f32x16;
typedef __attribute__((ext_vector_type(4)))  unsigned int uint4v;

typedef __attribute__((address_space(3))) void lds_void;
typedef __attribute__((address_space(1))) void g_void;

#if __has_builtin(__builtin_amdgcn_exp2f)
#define EXP2(x) __builtin_amdgcn_exp2f(x)
#else
#define EXP2(x) exp2f(x)
#endif

// async global->LDS, 16B per lane. LDS dest = wave-uniform base + lane*16.
__device__ __forceinline__ void gl_lds16(const void* g, void* l) {
    __builtin_amdgcn_global_load_lds((g_void*)(void*)g, (lds_void*)l, 16, 0, 0);
}

// pack 2 floats -> 2 bf16 in a dword (v_cvt_pk_bf16_f32)
__device__ __forceinline__ unsigned int pk2(float a, float b) {
    unsigned short ua = __builtin_bit_cast(unsigned short, (bf16)a);
    unsigned short ub = __builtin_bit_cast(unsigned short, (bf16)b);
    return (unsigned int)ua | ((unsigned int)ub << 16);
}

// key-axis permutation for V^T: swap bits 2<->3 (involution, closed within
// each 16-slot MFMA group). Makes PV's A-fragment lane-local (no shuffles).
__device__ __forceinline__ int ksw23(int x) {
    return (x & ~12) | ((x & 8) >> 1) | ((x & 4) << 1);
}

// ---------------- fused fp32 -> bf16 conversions (1 launch, G13) ----------
__global__ __launch_bounds__(256) void f2b_all(
    const float* __restrict__ x,  const float* __restrict__ wq,
    const float* __restrict__ wk, const float* __restrict__ wv,
    const float* __restrict__ wo,
    bf16* __restrict__ xb, bf16* __restrict__ wqkv, bf16* __restrict__ wob)
{
    int b = blockIdx.x;
    const float* src; bf16* dst; int base;
    if (b < 2048)      { src = x;  dst = xb;              base = b; }
    else if (b < 2560) { src = wq; dst = wqkv;            base = b - 2048; }
    else if (b < 3072) { src = wk; dst = wqkv + 1048576;  base = b - 2560; }
    else if (b < 3584) { src = wv; dst = wqkv + 2097152;  base = b - 3072; }
    else               { src = wo; dst = wob;             base = b - 3584; }
    int i = base * 2048 + threadIdx.x * 8;
    float4 a = *(const float4*)(src + i);
    float4 c = *(const float4*)(src + i + 4);
    bf16x8 r;
    r[0]=(bf16)a.x; r[1]=(bf16)a.y; r[2]=(bf16)a.z; r[3]=(bf16)a.w;
    r[4]=(bf16)c.x; r[5]=(bf16)c.y; r[6]=(bf16)c.z; r[7]=(bf16)c.w;
    *(bf16x8*)(dst + i) = r;
}

// ---------------- m97-style GEMM: C = A * B^T (A[M][K], B[N][K]) ----------
// MODE 0: fp32 out [M][N].
// MODE 1: QKV with FUSED per-head RMSNorm+RoPE epilogue for Q/K:
//   bn<8  -> Q: normalize+rotate fp32 acc, write outQ[h][s][d] bf16
//   bn<16 -> K: same, written pre-swizzled (d ^ ((s&7)<<3))
//   bn>=16-> V^T: outV = vt[H][64][S_LEN] with ksw23 key permutation and
//            (d&7)<<3 XOR pre-swizzle.
// Fusion layout fact: the 16 lanes sharing g hold all 64 dims of one
// head-row (cols n*16+r), so sum(x^2) = 4 in-lane squares + shfl_xor
// 1/2/4/8; the RoPE partner (d +/- 32) is IN-LANE (n <-> n^2).
template <int MODE>
__global__ __launch_bounds__(256) void gemm_bt(
    const bf16* __restrict__ A, const bf16* __restrict__ B,
    int M, int N, int K,
    float* __restrict__ outF,
    bf16* __restrict__ outQ, bf16* __restrict__ outK, bf16* __restrict__ outV,
    const float* __restrict__ cosb, const float* __restrict__ sinb,
    const float* __restrict__ qw,   const float* __restrict__ kw)
{
    __shared__ bf16 As[128][32];
    __shared__ bf16 Bs[128][32];
    const int bm = blockIdx.x, bn = blockIdx.y;
    const int tid  = threadIdx.x;
    const int wave = tid >> 6, lane = tid & 63;
    const int g = lane >> 4, r = lane & 15;
    const int wr = wave >> 1, wc = wave & 1;
    const int rr = lane >> 2, cc = (lane & 3) * 8;

    f32x4 acc[4][4] = {};

    const bf16* Ab = A + (size_t)(bm * 128) * K;
    const bf16* Bb = B + (size_t)(bn * 128) * K;

    for (int k0 = 0; k0 < K; k0 += 32) {
        #pragma unroll
        for (int i = 0; i < 2; ++i) {
            gl_lds16(Ab + (size_t)(wave*32 + i*16 + rr) * K + k0 + cc, &As[wave*32 + i*16][0]);
            gl_lds16(Bb + (size_t)(wave*32 + i*16 + rr) * K + k0 + cc, &Bs[wave*32 + i*16][0]);
        }
        __syncthreads();
        bf16x8 a[4], b[4];
        #pragma unroll
        for (int m = 0; m < 4; ++m) a[m] = *(const bf16x8*)&As[wr*64 + m*16 + r][g*8];
        #pragma unroll
        for (int n = 0; n < 4; ++n) b[n] = *(const bf16x8*)&Bs[wc*64 + n*16 + r][g*8];
        #pragma unroll
        for (int m = 0; m < 4; ++m)
            #pragma unroll
            for (int n = 0; n < 4; ++n)
                acc[m][n] = __builtin_amdgcn_mfma_f32_16x16x32_bf16(a[m], b[n], acc[m][n], 0, 0, 0);
        __syncthreads();
    }

    if (MODE == 0) {
        #pragma unroll
        for (int m = 0; m < 4; ++m)
            #pragma unroll
            for (int n = 0; n < 4; ++n)
                #pragma unroll
                for (int i = 0; i < 4; ++i) {
                    int row = bm*128 + wr*64 + m*16 + g*4 + i;
                    int col = bn*128 + wc*64 + n*16 + r;
                    outF[(size_t)row * N + col] = acc[m][n][i];
                }
    } else if (bn >= 16) {
        // V^T scatter with key permutation + pre-swizzle
        #pragma unroll
        for (int m = 0; m < 4; ++m)
            #pragma unroll
            for (int n = 0; n < 4; ++n)
                #pragma unroll
                for (int i = 0; i < 4; ++i) {
                    int row = bm*128 + wr*64 + m*16 + g*4 + i;
                    int col = bn*128 + wc*64 + n*16 + r;
                    int c2 = col - 2048;
                    int hh = c2 >> 6, d = c2 & 63;
                    int pos = ksw23(row & 63) ^ ((d & 7) << 3);
                    outV[((size_t)(hh * HD + d)) * S_LEN + (row & ~63) + pos] = (bf16)acc[m][n][i];
                }
    } else {
        // fused RMSNorm + RoPE for Q (bn<8) / K (8<=bn<16)
        const bool isK = (bn >= 8);
        const float* wn = isK ? kw : qw;
        bf16* dst = isK ? outK : outQ;
        const int h = ((bn & 7) << 1) | wc;
        float wv4[4];
        #pragma unroll
        for (int n = 0; n < 4; ++n) wv4[n] = wn[n * 16 + r];
        #pragma unroll
        for (int m = 0; m < 4; ++m)
            #pragma unroll
            for (int i = 0; i < 4; ++i) {
                int srow = bm*128 + wr*64 + m*16 + g*4 + i;
                float ss = acc[m][0][i]*acc[m][0][i] + acc[m][1][i]*acc[m][1][i]
                         + acc[m][2][i]*acc[m][2][i] + acc[m][3][i]*acc[m][3][i];
                ss += __shfl_xor(ss, 1);
                ss += __shfl_xor(ss, 2);
                ss += __shfl_xor(ss, 4);
                ss += __shfl_xor(ss, 8);
                float rn = rsqrtf(ss * (1.0f / 64.0f) + 1e-6f);
                float xn0 = acc[m][0][i] * rn * wv4[0];
                float xn1 = acc[m][1][i] * rn * wv4[1];
                float xn2 = acc[m][2][i] * rn * wv4[2];
                float xn3 = acc[m][3][i] * rn * wv4[3];
                float c0 = cosb[srow * 32 + r],      c1 = cosb[srow * 32 + 16 + r];
                float s0 = sinb[srow * 32 + r],      s1 = sinb[srow * 32 + 16 + r];
                float y0 = xn0 * c0 - xn2 * s0;
                float y1 = xn1 * c1 - xn3 * s1;
                float y2 = xn2 * c0 + xn0 * s0;
                float y3 = xn3 * c1 + xn1 * s1;
                size_t ob = ((size_t)h * S_LEN + srow) * HD;
                if (isK) {
                    int sw = (srow & 7) << 3;
                    dst[ob + ((     r) ^ sw)] = (bf16)y0;
                    dst[ob + ((16 + r) ^ sw)] = (bf16)y1;
                    dst[ob + ((32 + r) ^ sw)] = (bf16)y2;
                    dst[ob + ((48 + r) ^ sw)] = (bf16)y3;
                } else {
                    dst[ob +      r] = (bf16)y0;
                    dst[ob + 16 + r] = (bf16)y1;
                    dst[ob + 32 + r] = (bf16)y2;
                    dst[ob + 48 + r] = (bf16)y3;
                }
            }
    }
}

// ---------------- causal flash attention, 32x32 MFMA, 4-chunk split -------
// 2048 blocks = queue at 4/CU (proven: 62.3us, 64 VGPR, no spill).
// idx: h = idx&15; u = idx>>4: qt = 31-(u>>2) (LPT order), c = u&3;
// tiles t in [c*nt/4, (c+1)*nt/4), nt = 2qt+2. Static-max softmax (diag
// score = +8 exactly): P = exp2(S*C1 - C2) -- pure sums, chunk partials
// (bf16 O slabs + fp32 l) combine by addition.
// Swapped QK^T: lane q = lane&31 owns its q-row's P at
// k = kn*32 + (rg&3) + 8*(rg>>2) + 4*hi (verified 32x32 C/D layout).
// V^T pre-permuted (ksw23) + XOR-swizzled -> PV A-fragment is lane-local.
// Unroll-2 via MACRO (r9: outlined fat lambda spilled captures -> 450MB
// scratch; macro guarantees textual inlining with literal buffer indices).
__global__ __launch_bounds__(256, 4) void attn_kernel(
    const bf16* __restrict__ q, const bf16* __restrict__ k,
    const bf16* __restrict__ vt,
    bf16* __restrict__ Opc, float* __restrict__ lpc)
{
    __shared__ bf16 Ks[2][64][64];   // [keys][d], rows pre-swizzled
    __shared__ bf16 Vt[2][64][64];   // [d][keys], permuted+pre-swizzled

    const int idx = blockIdx.x;
    const int h = idx & 15;
    const int u = idx >> 4;
    const int qt = 31 - (u >> 2);
    const int c  = u & 3;
    const int nt = 2 * qt + 2;
    const int t0 = (c * nt) >> 2;
    const int t1 = ((c + 1) * nt) >> 2;

    const int q0 = qt * 128;
    const int tid = threadIdx.x;
    const int wave = tid >> 6, lane = tid & 63;
    const int l31 = lane & 31, hi = lane >> 5;

    const bf16* qh  = q  + (size_t)h * S_LEN * HD;
    const bf16* kh  = k  + (size_t)h * S_LEN * HD;
    const bf16* vth = vt + (size_t)h * HD * S_LEN;

    const int qrow = q0 + wave * 32 + l31;
    bf16x8 qf[4];
    #pragma unroll
    for (int ds4 = 0; ds4 < 4; ++ds4)
        qf[ds4] = *(const bf16x8*)(qh + (size_t)qrow * HD + ds4 * 16 + hi * 8);

    float l_run = 0.f;
    f32x16 acc_o[2] = {};

    const int srow = lane >> 3, scol = (lane & 7) * 8;
    const float C1 = 0.125f * 1.44269504088896f;   // scale * log2(e)
    const float C2 = 8.0f * 1.44269504088896f;     // static max * log2(e)

    auto stage = [&](int t, int buf) {
        const int k0 = t * 64;
        const bf16* kb = kh + (size_t)(k0 + wave * 16) * HD;
        gl_lds16(kb + (size_t)(srow    ) * HD + scol, &Ks[buf][wave * 16][0]);
        gl_lds16(kb + (size_t)(srow + 8) * HD + scol, &Ks[buf][wave * 16 + 8][0]);
        const bf16* vb = vth + (size_t)(wave * 16) * S_LEN + k0;
        gl_lds16(vb + (size_t)(srow    ) * S_LEN + scol, &Vt[buf][wave * 16][0]);
        gl_lds16(vb + (size_t)(srow + 8) * S_LEN + scol, &Vt[buf][wave * 16 + 8][0]);
    };

#define COMPUTE_TILE(T, BUF)                                                  \
    do {                                                                      \
        const int k0_ = (T) * 64;                                             \
        const bool masked_ = ((T) >= 2 * qt);                                 \
        f32x16 sacc_[2];                                                      \
        __builtin_amdgcn_s_setprio(1);                                        \
        _Pragma("unroll")                                                     \
        for (int kn = 0; kn < 2; ++kn) {                                      \
            const int krow = kn * 32 + l31;                                   \
            const int sw = (krow & 7) << 3;                                   \
            f32x16 z = {};                                                    \
            _Pragma("unroll")                                                 \
            for (int ds4 = 0; ds4 < 4; ++ds4) {                               \
                bf16x8 kfr = *(const bf16x8*)&Ks[BUF][krow][(ds4 * 16 + hi * 8) ^ sw]; \
                z = __builtin_amdgcn_mfma_f32_32x32x16_bf16(kfr, qf[ds4], z, 0, 0, 0); \
            }                                                                 \
            sacc_[kn] = z;                                                    \
        }                                                                     \
        __builtin_amdgcn_s_setprio(0);                                        \
        float p_[32];                                                         \
        _Pragma("unroll")                                                     \
        for (int kn = 0; kn < 2; ++kn)                                        \
            _Pragma("unroll")                                                 \
            for (int rg = 0; rg < 16; ++rg) {                                 \
                float e = EXP2(fmaf(sacc_[kn][rg], C1, -C2));                 \
                if (masked_) {                                                \
                    int kloc = kn * 32 + (rg & 3) + 8 * (rg >> 2) + 4 * hi;   \
                    if (k0_ + kloc > qrow) e = 0.f;                           \
                }                                                             \
                p_[kn * 16 + rg] = e;                                         \
            }                                                                 \
        float s0_ = 0.f, s1_ = 0.f, s2_ = 0.f, s3_ = 0.f;                     \
        _Pragma("unroll")                                                     \
        for (int j = 0; j < 8; ++j) {                                         \
            s0_ += p_[4*j];   s1_ += p_[4*j+1];                               \
            s2_ += p_[4*j+2]; s3_ += p_[4*j+3];                               \
        }                                                                     \
        float rs_ = (s0_ + s1_) + (s2_ + s3_);                                \
        rs_ += __shfl_xor(rs_, 32);                                           \
        l_run += rs_;                                                         \
        bf16x8 pa_[4];                                                        \
        _Pragma("unroll")                                                     \
        for (int ks4 = 0; ks4 < 4; ++ks4) {                                   \
            uint4v w_;                                                        \
            w_.x = pk2(p_[8*ks4+0], p_[8*ks4+1]);                             \
            w_.y = pk2(p_[8*ks4+2], p_[8*ks4+3]);                             \
            w_.z = pk2(p_[8*ks4+4], p_[8*ks4+5]);                             \
            w_.w = pk2(p_[8*ks4+6], p_[8*ks4+7]);                             \
            pa_[ks4] = __builtin_bit_cast(bf16x8, w_);                        \
        }                                                                     \
        __builtin_amdgcn_s_setprio(1);                                        \
        _Pragma("unroll")                                                     \
        for (int n = 0; n < 2; ++n) {                                         \
            const int d = n * 32 + l31;                                       \
            const int sw = (d & 7) << 3;                                      \
            f32x16 a = acc_o[n];                                              \
            _Pragma("unroll")                                                 \
            for (int ks4 = 0; ks4 < 4; ++ks4) {                               \
                bf16x8 vfr = *(const bf16x8*)&Vt[BUF][d][(ks4 * 16 + hi * 8) ^ sw]; \
                a = __builtin_amdgcn_mfma_f32_32x32x16_bf16(pa_[ks4], vfr, a, 0, 0, 0); \
            }                                                                 \
            acc_o[n] = a;                                                     \
        }                                                                     \
        __builtin_amdgcn_s_setprio(0);                                        \
    } while (0)

    if (t0 < t1) {
        stage(t0, 0);
        asm volatile("s_waitcnt vmcnt(0)" ::: "memory");
        __syncthreads();
        int t = t0;
        while (t + 2 <= t1) {
            stage(t + 1, 1);
            COMPUTE_TILE(t, 0);
            asm volatile("s_waitcnt vmcnt(0)" ::: "memory");
            __syncthreads();
            if (t + 2 < t1) stage(t + 2, 0);
            COMPUTE_TILE(t + 1, 1);
            asm volatile("s_waitcnt vmcnt(0)" ::: "memory");
            __syncthreads();
            t += 2;
        }
        if (t < t1) COMPUTE_TILE(t, 0);   // odd tail (already staged in buf0)
    }
#undef COMPUTE_TILE

    // partial epilogue: bf16 O slab for this chunk + fp32 l. C/D: col = l31,
    // row q = (rg&3) + 8*(rg>>2) + 4*hi. Empty chunks write zeros.
    bf16* Op = Opc + (size_t)c * S_LEN * DIM;
    #pragma unroll
    for (int n = 0; n < 2; ++n)
        #pragma unroll
        for (int rg = 0; rg < 16; ++rg) {
            int s_abs = q0 + wave * 32 + (rg & 3) + 8 * (rg >> 2) + 4 * hi;
            Op[(size_t)s_abs * DIM + h * HD + n * 32 + l31] = (bf16)acc_o[n][rg];
        }
    if (lane < 32)
        lpc[c * (NH * S_LEN) + h * S_LEN + (q0 + wave * 32 + lane)] = l_run;
}

// ---------------- combine 4 chunk partials + normalize -> bf16 ------------
// o may alias Opc slab 0: each thread reads all 4 slabs at its elements
// before writing them (element-wise, single-thread ownership -> safe).
__global__ __launch_bounds__(256) void combine_kernel(
    const bf16* __restrict__ Opc, const float* __restrict__ lpc,
    bf16* __restrict__ o)
{
    int gid = blockIdx.x * 256 + threadIdx.x;
    int e = gid * 8;
    int s = e >> 10, h = (e & 1023) >> 6;
    float a[8] = {};
    #pragma unroll
    for (int c = 0; c < 4; ++c) {
        bf16x8 v = *(const bf16x8*)(Opc + (size_t)c * S_LEN * DIM + e);
        #pragma unroll
        for (int j = 0; j < 8; ++j) a[j] += (float)v[j];
    }
    float l = 0.f;
    #pragma unroll
    for (int c = 0; c < 4; ++c) l += lpc[c * (NH * S_LEN) + h * S_LEN + s];
    float inv = __builtin_amdgcn_rcpf(l);
    bf16x8 rv;
    #pragma unroll
    for (int j = 0; j < 8; ++j) rv[j] = (bf16)(a[j] * inv);
    *(bf16x8*)(o + e) = rv;
}

// ---------------------------------------------------------------------------
extern "C" void kernel_launch(void* const* d_in, const int* in_sizes, int n_in,
                              void* d_out, int out_size, void* d_ws, size_t ws_size,
                              hipStream_t stream)
{
    const float* x    = (const float*)d_in[0];
    const float* cosb = (const float*)d_in[1];
    const float* sinb = (const float*)d_in[2];
    const float* wq   = (const float*)d_in[4];
    const float* wk   = (const float*)d_in[5];
    const float* wv   = (const float*)d_in[6];
    const float* wo   = (const float*)d_in[7];
    const float* qw   = (const float*)d_in[8];
    const float* kw   = (const float*)d_in[9];

    char* ws = (char*)d_ws;
    const size_t MB = 1024 * 1024;
    // region map (MB), temporal reuse (59MB total):
    // [0,2)   wob (whole run)
    // [2,10)  q_ws  (gemm_bt<1> fused epilogue -> attn)
    // [10,18) k_ws  (pre-swizzled)
    // [18,26) vt_ws (pre-permuted V^T)
    // [26,58) Opc[4] bf16 slabs (attn->combine); before attn this region
    //         hosts xb [26,34) + wqkv [34,40) (both dead after QKV GEMM);
    //         o_ws = slab0 [26,34) (combine writes in-place, elementwise)
    // [58,59) lpc[4] fp32
    bf16*  wob   = (bf16*)(ws + 0);
    bf16*  q_ws  = (bf16*)(ws + 2 * MB);
    bf16*  k_ws  = (bf16*)(ws + 10 * MB);
    bf16*  vt_ws = (bf16*)(ws + 18 * MB);
    bf16*  Opc   = (bf16*)(ws + 26 * MB);
    bf16*  o_ws  = (bf16*)(ws + 26 * MB);
    bf16*  xb    = (bf16*)(ws + 26 * MB);
    bf16*  wqkv  = (bf16*)(ws + 34 * MB);
    float* lpc   = (float*)(ws + 58 * MB);

    f2b_all<<<4096, 256, 0, stream>>>(x, wq, wk, wv, wo, xb, wqkv, wob);

    gemm_bt<1><<<dim3(32, 24), 256, 0, stream>>>(xb, wqkv, 4096, 3072, 1024,
                                                 nullptr, q_ws, k_ws, vt_ws,
                                                 cosb, sinb, qw, kw);
    attn_kernel<<<2048, 256, 0, stream>>>(q_ws, k_ws, vt_ws, Opc, lpc);
    combine_kernel<<<4096 * 1024 / 8 / 256, 256, 0, stream>>>(Opc, lpc, o_ws);
    gemm_bt<0><<<dim3(32, 8), 256, 0, stream>>>(o_ws, wob, 4096, 1024, 1024,
                                                (float*)d_out, nullptr, nullptr, nullptr,
                                                nullptr, nullptr, nullptr, nullptr);
}